// Round 16
// baseline (1998.851 us; speedup 1.0000x reference)
//
#include <hip/hip_runtime.h>
#include <hip/hip_bf16.h>

// B=4, N=8192, S=2048, C=128, c_in=131, c_out=256, K=20 (fixed by setup_inputs).
// Algebra: h = (knn_feat-center)@W1 + center@W2 = P[knn_idx] + Q.
// BN(gamma>0) and ReLU monotone => max_k commutes.
//
// r14/r15 diagnostics: fps chain floor ~997cy/iter is barrier/latency-structural;
// atomicMax combine is NOT the cost (store+fold slightly worse). r16:
//  (1) fps v14 = v10 (best measured, 1525) + exact hierarchical wave pretest.
//  (2) mega-kernel: fps(4 blk) + matmulP(128 blk) + wdiff(33 blk) in ONE launch
//      -> matmulP/wdiff run on the 252 idle CUs in fps's shadow (no deps).

#define NPTS   8192
#define NSAMP  2048
#define KNN    20

typedef unsigned long long u64;
typedef unsigned int u32;
typedef unsigned short u16;

// ---------- DPP reduction helpers (wave64; validated on HW rounds 5-15) ----------
template<int CTRL, int RM>
__device__ __forceinline__ u64 dpp_kmax(u64 k) {
  unsigned lo = (unsigned)k, hi = (unsigned)(k >> 32);
  unsigned lo2 = (unsigned)__builtin_amdgcn_update_dpp((int)lo, (int)lo, CTRL, RM, 0xf, false);
  unsigned hi2 = (unsigned)__builtin_amdgcn_update_dpp((int)hi, (int)hi, CTRL, RM, 0xf, false);
  u64 o = ((u64)hi2 << 32) | lo2;
  return o > k ? o : k;
}
template<int CTRL, int RM>
__device__ __forceinline__ u64 dpp_kmin(u64 k) {
  unsigned lo = (unsigned)k, hi = (unsigned)(k >> 32);
  unsigned lo2 = (unsigned)__builtin_amdgcn_update_dpp((int)lo, (int)lo, CTRL, RM, 0xf, false);
  unsigned hi2 = (unsigned)__builtin_amdgcn_update_dpp((int)hi, (int)hi, CTRL, RM, 0xf, false);
  u64 o = ((u64)hi2 << 32) | lo2;
  return o < k ? o : k;
}
template<int CTRL, int RM>
__device__ __forceinline__ float dpp_fmax(float x) {
  int t = __builtin_amdgcn_update_dpp(__float_as_int(x), __float_as_int(x), CTRL, RM, 0xf, false);
  return fmaxf(x, __int_as_float(t));
}
template<int CTRL, int RM>
__device__ __forceinline__ float dpp_fmin(float x) {
  int t = __builtin_amdgcn_update_dpp(__float_as_int(x), __float_as_int(x), CTRL, RM, 0xf, false);
  return fminf(x, __int_as_float(t));
}
__device__ __forceinline__ u64 umax64(u64 a, u64 b) { return a > b ? a : b; }

__device__ __forceinline__ float wave_fmax_bcast(float x) {
  x = dpp_fmax<0xB1, 0xf>(x); x = dpp_fmax<0x4E, 0xf>(x);
  x = dpp_fmax<0x124, 0xf>(x); x = dpp_fmax<0x128, 0xf>(x);
  x = dpp_fmax<0x142, 0xa>(x); x = dpp_fmax<0x143, 0xc>(x);
  return __int_as_float(__builtin_amdgcn_readlane(__float_as_int(x), 63));
}
__device__ __forceinline__ float wave_fmin_bcast(float x) {
  x = dpp_fmin<0xB1, 0xf>(x); x = dpp_fmin<0x4E, 0xf>(x);
  x = dpp_fmin<0x124, 0xf>(x); x = dpp_fmin<0x128, 0xf>(x);
  x = dpp_fmin<0x142, 0xa>(x); x = dpp_fmin<0x143, 0xc>(x);
  return __int_as_float(__builtin_amdgcn_readlane(__float_as_int(x), 63));
}

__device__ __forceinline__ unsigned mspread4(unsigned q) {  // 4b -> every 3rd bit
  return (q & 1u) | ((q & 2u) << 2) | ((q & 4u) << 4) | ((q & 8u) << 6);
}

// Mega kernel: blocks 0-3 = FPS v14; 4..3+NM = matmulP (bf16, 256 rows/block,
// 8x 32-row subtiles); rest = wdiff. No inter-block dependencies.
#define NM_BLOCKS 128
__global__ __launch_bounds__(1024, 1) void mega_kernel(
    const float* __restrict__ xyz, const int* __restrict__ farthest0,
    const float* __restrict__ feat, const float* __restrict__ conv_w,
    int* __restrict__ sample_int, float* __restrict__ out,
    __hip_bfloat16* __restrict__ Pb, float* __restrict__ Wd, int nmatmul) {
  __shared__ u64 smem8[17984];              // 143,872 B (fps 143,388 / matmul 135,168)
  char* smem = (char*)smem8;
  const int bid = blockIdx.x, tid = threadIdx.x;

  if (bid >= 4) {
    if (bid - 4 < nmatmul) {
      // ---- matmulP: OUT[row,c] = sum_k feat_aug[row][k] * W1[k*256+c], bf16 out ----
      float* tile = (float*)smem + (tid >> 7) * (32 * 132);  // [32][132] per group
      const int gtid = tid & 127;
      const int r0 = (bid - 4) * 256 + (tid >> 7) * 32;
      for (int i = gtid; i < 32 * 131; i += 128) {
        int r = i / 131;
        int k = i - r * 131;
        int src = r0 + r;                  // global row 0..32767
        float v = (k < 128) ? feat[(size_t)src * 128 + k]
                            : xyz[(size_t)src * 3 + (k - 128)];
        tile[r * 132 + k] = v;
      }
      __syncthreads();
      float acc0[32], acc1[32];
#pragma unroll
      for (int r = 0; r < 32; ++r) { acc0[r] = 0.f; acc1[r] = 0.f; }
      const int c0 = gtid, c1 = gtid + 128;
      for (int k = 0; k < 128; k += 4) {
        float w00 = conv_w[(k+0)*256+c0], w01 = conv_w[(k+1)*256+c0], w02 = conv_w[(k+2)*256+c0], w03 = conv_w[(k+3)*256+c0];
        float w10 = conv_w[(k+0)*256+c1], w11 = conv_w[(k+1)*256+c1], w12 = conv_w[(k+2)*256+c1], w13 = conv_w[(k+3)*256+c1];
#pragma unroll
        for (int r = 0; r < 32; ++r) {
          float4 a = *(const float4*)&tile[r * 132 + k];
          acc0[r] = fmaf(a.x, w00, acc0[r]); acc0[r] = fmaf(a.y, w01, acc0[r]);
          acc0[r] = fmaf(a.z, w02, acc0[r]); acc0[r] = fmaf(a.w, w03, acc0[r]);
          acc1[r] = fmaf(a.x, w10, acc1[r]); acc1[r] = fmaf(a.y, w11, acc1[r]);
          acc1[r] = fmaf(a.z, w12, acc1[r]); acc1[r] = fmaf(a.w, w13, acc1[r]);
        }
      }
#pragma unroll
      for (int kk = 128; kk < 131; ++kk) {
        float w0 = conv_w[kk*256+c0], w1 = conv_w[kk*256+c1];
#pragma unroll
        for (int r = 0; r < 32; ++r) {
          float a = tile[r * 132 + kk];
          acc0[r] = fmaf(a, w0, acc0[r]);
          acc1[r] = fmaf(a, w1, acc1[r]);
        }
      }
#pragma unroll
      for (int r = 0; r < 32; ++r) {
        Pb[(size_t)(r0 + r) * 256 + c0] = __float2bfloat16(acc0[r]);
        Pb[(size_t)(r0 + r) * 256 + c1] = __float2bfloat16(acc1[r]);
      }
    } else {
      // ---- wdiff: Wd = W2 - W1 ----
      int i = (bid - 4 - nmatmul) * 1024 + tid;
      if (i < 131 * 256) Wd[i] = conv_w[131 * 256 + i] - conv_w[i];
    }
    return;
  }

  // ================= FPS v14 (blocks 0-3) =================
  float* sxyz  = (float*)smem;              // [24576]
  u16*   sidxr = (u16*)(smem + 98304);      // [8192]
  u32*   s_samp= (u32*)(smem + 114688);     // [2048]
  u32*   hist  = (u32*)(smem + 122880);     // [4096]
  u32*   part  = (u32*)(smem + 139264);     // [1024]
  u64*   slot  = (u64*)(smem + 143360);     // [3]
  int*   s_isp = (int*)(smem + 143384);
  const int b = bid, lane = tid & 63;
  const float* xb = xyz + (size_t)b * NPTS * 3;

  // ---- counting sort by 12-bit Morton (4 bits/axis, range [-5.2, 5.2]) ----
  for (int i = tid; i < 4096; i += 1024) hist[i] = 0u;
  if (tid < 3) slot[tid] = 0ull;
  __syncthreads();

  float ox[8], oy[8], oz[8];
  int cell[8];
#pragma unroll
  for (int j = 0; j < 8; ++j) {
    int p = tid * 8 + j;
    float x = xb[3*p], y = xb[3*p+1], z = xb[3*p+2];
    ox[j] = x; oy[j] = y; oz[j] = z;
    unsigned qx = (unsigned)(int)fminf(fmaxf((x + 5.2f) * 1.5384615f, 0.f), 15.f);
    unsigned qy = (unsigned)(int)fminf(fmaxf((y + 5.2f) * 1.5384615f, 0.f), 15.f);
    unsigned qz = (unsigned)(int)fminf(fmaxf((z + 5.2f) * 1.5384615f, 0.f), 15.f);
    cell[j] = (int)(mspread4(qx) | (mspread4(qy) << 1) | (mspread4(qz) << 2));
    atomicAdd(&hist[cell[j]], 1u);
  }
  __syncthreads();

  u32 h0 = hist[4*tid], h1 = hist[4*tid+1], h2 = hist[4*tid+2], h3 = hist[4*tid+3];
  u32 mysum = h0 + h1 + h2 + h3;
  part[tid] = mysum;
  __syncthreads();
  for (int off = 1; off < 1024; off <<= 1) {
    u32 u = (tid >= off) ? part[tid - off] : 0u;
    u32 v = part[tid];
    __syncthreads();
    part[tid] = u + v;
    __syncthreads();
  }
  u32 base = part[tid] - mysum;
  hist[4*tid]   = base;
  hist[4*tid+1] = base + h0;
  hist[4*tid+2] = base + h0 + h1;
  hist[4*tid+3] = base + h0 + h1 + h2;
  __syncthreads();

#pragma unroll
  for (int j = 0; j < 8; ++j) {
    u32 p = atomicAdd(&hist[cell[j]], 1u);
    sxyz[3*p] = ox[j]; sxyz[3*p+1] = oy[j]; sxyz[3*p+2] = oz[j];
    sidxr[p] = (u16)(tid * 8 + j);
  }
  __syncthreads();

  const int cur0 = farthest0[b];
#pragma unroll
  for (int j = 0; j < 8; ++j) {
    int p = tid * 8 + j;
    if ((int)sidxr[p] == cur0) *s_isp = p;  // exactly one writer
  }

  // ---- per-lane bucket: 8 sorted-consecutive points + tight per-lane bbox ----
  float px[8], py[8], pz[8], dist[8];
  u32 low32[8];                             // (~orig:13)<<13 | sp:13
#pragma unroll
  for (int j = 0; j < 8; ++j) {
    int p = tid * 8 + j;
    px[j] = sxyz[3*p]; py[j] = sxyz[3*p+1]; pz[j] = sxyz[3*p+2];
    low32[j] = (((~(u32)sidxr[p]) & 0x1FFFu) << 13) | (u32)p;
    dist[j] = 1e10f;                        // reference init 10000000000.0
  }
  float lxmin = px[0], lxmax = px[0], lymin = py[0], lymax = py[0], lzmin = pz[0], lzmax = pz[0];
#pragma unroll
  for (int j = 1; j < 8; ++j) {
    lxmin = fminf(lxmin, px[j]); lxmax = fmaxf(lxmax, px[j]);
    lymin = fminf(lymin, py[j]); lymax = fmaxf(lymax, py[j]);
    lzmin = fminf(lzmin, pz[j]); lzmax = fmaxf(lzmax, pz[j]);
  }
  // wave bbox (uniform after bcast) for the hierarchical pretest
  const float wxmin = wave_fmin_bcast(lxmin), wxmax = wave_fmax_bcast(lxmax);
  const float wymin = wave_fmin_bcast(lymin), wymax = wave_fmax_bcast(lymax);
  const float wzmin = wave_fmin_bcast(lzmin), wzmax = wave_fmax_bcast(lzmax);

  u64 klane = ((u64)__float_as_uint(1e10f) << 32);  // per-lane cached max key
  u64 kw    = ((u64)__float_as_uint(1e10f) << 32);  // lane63 holds wave max after fold
  __syncthreads();                                  // s_isp visible

  int cur_sp = *s_isp;
  u32 cur_pack = ((u32)cur0 << 13) | (u32)cur_sp;

  for (int it = 0; it < NSAMP; ++it) {
    if (tid == 0) s_samp[it] = cur_pack;   // scan emits carry (index before update)
    if (it == NSAMP - 1) break;
    if (tid == 64) slot[(it+2)%3] = 0ull;  // rotation proven race-free (v6-v13)
    float3 c3 = *(const float3*)&sxyz[3*cur_sp];   // one ds_read_b96, uniform
    float cx = c3.x, cy = c3.y, cz = c3.z;

    // ---- hierarchical wave pretest (uniform; exact: wave_bound <= lane_bound,
    // ubw >= lane_ub, so skip here implies every lane's skip condition) ----
    float wgx = fmaxf(fmaxf(__fsub_rn(wxmin, cx), __fsub_rn(cx, wxmax)), 0.f);
    float wgy = fmaxf(fmaxf(__fsub_rn(wymin, cy), __fsub_rn(cy, wymax)), 0.f);
    float wgz = fmaxf(fmaxf(__fsub_rn(wzmin, cz), __fsub_rn(cz, wzmax)), 0.f);
    float wbound = __fadd_rn(__fadd_rn(__fmul_rn(wgx,wgx), __fmul_rn(wgy,wgy)), __fmul_rn(wgz,wgz));
    float ubw = __int_as_float(__builtin_amdgcn_readlane((int)(u32)(kw >> 32), 63));
    if (!(__fmul_rn(wbound, 0.999999f) >= ubw)) {   // wave-uniform branch
      // per-lane exact skip: bound >= lane max dist => bucket unchanged
      float gx = fmaxf(fmaxf(__fsub_rn(lxmin, cx), __fsub_rn(cx, lxmax)), 0.f);
      float gy = fmaxf(fmaxf(__fsub_rn(lymin, cy), __fsub_rn(cy, lymax)), 0.f);
      float gz = fmaxf(fmaxf(__fsub_rn(lzmin, cz), __fsub_rn(cz, lzmax)), 0.f);
      float bound = __fadd_rn(__fadd_rn(__fmul_rn(gx,gx), __fmul_rn(gy,gy)), __fmul_rn(gz,gz));
      float ub = __uint_as_float((u32)(klane >> 32));
      bool live = !(__fmul_rn(bound, 0.999999f) >= ub);

      if (__any(live)) {
        if (live) {
          // strict IEEE update, no FMA contraction (matches reference bit-exact)
#pragma unroll
          for (int j = 0; j < 8; ++j) {
            float dx = __fsub_rn(px[j], cx);
            float dy = __fsub_rn(py[j], cy);
            float dz = __fsub_rn(pz[j], cz);
            float d  = __fadd_rn(__fadd_rn(__fmul_rn(dx,dx), __fmul_rn(dy,dy)), __fmul_rn(dz,dz));
            dist[j] = fminf(dist[j], d);
          }
          u64 k0 = ((u64)__float_as_uint(dist[0]) << 32) | low32[0];
          u64 k1 = ((u64)__float_as_uint(dist[1]) << 32) | low32[1];
          u64 k2 = ((u64)__float_as_uint(dist[2]) << 32) | low32[2];
          u64 k3 = ((u64)__float_as_uint(dist[3]) << 32) | low32[3];
          u64 k4 = ((u64)__float_as_uint(dist[4]) << 32) | low32[4];
          u64 k5 = ((u64)__float_as_uint(dist[5]) << 32) | low32[5];
          u64 k6 = ((u64)__float_as_uint(dist[6]) << 32) | low32[6];
          u64 k7 = ((u64)__float_as_uint(dist[7]) << 32) | low32[7];
          klane = umax64(umax64(umax64(k0,k1), umax64(k2,k3)),
                         umax64(umax64(k4,k5), umax64(k6,k7)));
        }
        u64 k = klane;                     // dead lanes contribute valid cache
        k = dpp_kmax<0xB1, 0xf>(k);
        k = dpp_kmax<0x4E, 0xf>(k);
        k = dpp_kmax<0x124, 0xf>(k);
        k = dpp_kmax<0x128, 0xf>(k);
        k = dpp_kmax<0x142, 0xa>(k);
        k = dpp_kmax<0x143, 0xc>(k);
        kw = k;                            // lane 63 holds the wave max
      }
    }
    if (lane == 63) atomicMax(&slot[(it+1)%3], kw);
    __syncthreads();                       // the ONLY barrier per iteration
    u64 wk = slot[(it+1)%3];               // uniform LDS read
    u32 wlo = (u32)wk;
    cur_sp = (int)(wlo & 0x1FFFu);
    u32 org = (~(wlo >> 13)) & 0x1FFFu;
    cur_pack = (org << 13) | (u32)cur_sp;
  }

  __syncthreads();
  float* outxyz = out + (size_t)b * NSAMP * 3;
  float* outidx = out + 24576 + 2097152 + (size_t)b * NSAMP;
  for (int it = tid; it < NSAMP; it += 1024) {
    u32 s = s_samp[it];
    int org = (int)(s >> 13), sp = (int)(s & 0x1FFFu);
    sample_int[(b << 11) + it] = org;
    outidx[it] = (float)org;
    outxyz[3*it]   = sxyz[3*sp];
    outxyz[3*it+1] = sxyz[3*sp+1];
    outxyz[3*it+2] = sxyz[3*sp+2];
  }
}

// kNN v5 (r10-r15): 2 waves per query, exact rank-merge of two sorted top-20 lists.
__global__ __launch_bounds__(256, 1) void knn_kernel(
    const float* __restrict__ xyz, const int* __restrict__ sample_int,
    int* __restrict__ knn_out) {
  __shared__ u64 lists[2][2][KNN];
  const int tid  = threadIdx.x;
  const int lane = tid & 63, w = tid >> 6;
  const int ql   = w >> 1;                 // local query 0..1
  const int ch   = w & 1;                  // chunk 0..1
  const int qq   = blockIdx.x * 2 + ql;
  const int b    = qq >> 11;
  const float* xb = xyz + (size_t)b * NPTS * 3;
  const int sidx = sample_int[qq];
  const float sx = xb[3*sidx], sy = xb[3*sidx+1], sz = xb[3*sidx+2];
  const float sqs = __fadd_rn(__fadd_rn(__fmul_rn(sx,sx), __fmul_rn(sy,sy)), __fmul_rn(sz,sz));

  const int pbase = ch * 4096;
  float d[64];
#pragma unroll
  for (int i = 0; i < 64; ++i) {
    int p = pbase + i*64 + lane;
    float x = xb[3*p], y = xb[3*p+1], z = xb[3*p+2];
    float dot = __fadd_rn(__fadd_rn(__fmul_rn(sx,x), __fmul_rn(sy,y)), __fmul_rn(sz,z));
    float sqx = __fadd_rn(__fadd_rn(__fmul_rn(x,x), __fmul_rn(y,y)), __fmul_rn(z,z));
    d[i] = __fadd_rn(__fsub_rn(sqs, __fmul_rn(2.0f, dot)), sqx);  // (||s||^2-2dot)+||x||^2
  }
  u64 msk = 0ull;
  for (int kk = 0; kk < KNN; ++kk) {
    float bv = 1e30f; int bs = 0;
#pragma unroll
    for (int i = 0; i < 64; ++i) {
      float dc = (msk & (1ull << i)) ? 1e30f : d[i];
      if (dc < bv) { bv = dc; bs = i; }   // strict <: smallest slot on ties
    }
    unsigned gi = (unsigned)(pbase + bs*64 + lane);
    u64 key = ((u64)__float_as_uint(bv) << 32) | gi;
    key = dpp_kmin<0xB1, 0xf>(key);
    key = dpp_kmin<0x4E, 0xf>(key);
    key = dpp_kmin<0x124, 0xf>(key);
    key = dpp_kmin<0x128, 0xf>(key);
    key = dpp_kmin<0x142, 0xa>(key);
    key = dpp_kmin<0x143, 0xc>(key);
    unsigned glo = (unsigned)__builtin_amdgcn_readlane((int)(unsigned)key, 63);
    unsigned ghi = (unsigned)__builtin_amdgcn_readlane((int)(unsigned)(key >> 32), 63);
    if (lane == (int)(glo & 63u)) msk |= 1ull << ((glo - pbase) >> 6);
    if (lane == 0) lists[ql][ch][kk] = ((u64)ghi << 32) | glo;
  }
  __syncthreads();
  if (ch == 0) {
    u64 mykey = ~0ull; int rank = 64;
    if (lane < 40) {
      int li = lane >= 20 ? 1 : 0;
      int e  = li ? lane - 20 : lane;
      mykey = lists[ql][li][e];
      int cnt = e;
      const u64* oth = &lists[ql][li ^ 1][0];
#pragma unroll
      for (int j = 0; j < KNN; ++j) cnt += (oth[j] < mykey) ? 1 : 0;
      rank = cnt;
    }
    if (rank < KNN) knn_out[(size_t)qq * KNN + rank] = (int)(mykey & 0xFFFFFFFFull);
  }
}

// matmul131 (generic): used for Q = center@(W2-W1) and the non-fused fallback.
template<bool BF16OUT>
__global__ __launch_bounds__(128) void matmul131_kernel(
    const float* __restrict__ featb, const float* __restrict__ xyzb,
    const int* __restrict__ gidx,
    const float* __restrict__ W, void* __restrict__ outp) {
  __shared__ float tile[32][132];
  const int tid = threadIdx.x;
  const int r0  = blockIdx.x << 5;
  for (int i = tid; i < 32*131; i += 128) {
    int r = i / 131;
    int k = i - r*131;
    int row = r0 + r;
    int src;
    if (gidx) { int bb = row >> 11; src = (bb << 13) + gidx[row]; }
    else      { src = row; }
    float v = (k < 128) ? featb[(size_t)src*128 + k]
                        : xyzb[(size_t)src*3 + (k-128)];
    tile[r][k] = v;
  }
  __syncthreads();
  float acc0[32], acc1[32];
#pragma unroll
  for (int r = 0; r < 32; ++r) { acc0[r] = 0.f; acc1[r] = 0.f; }
  const int c0 = tid, c1 = tid + 128;
  for (int k = 0; k < 128; k += 4) {
    float w00 = W[(k+0)*256+c0], w01 = W[(k+1)*256+c0], w02 = W[(k+2)*256+c0], w03 = W[(k+3)*256+c0];
    float w10 = W[(k+0)*256+c1], w11 = W[(k+1)*256+c1], w12 = W[(k+2)*256+c1], w13 = W[(k+3)*256+c1];
#pragma unroll
    for (int r = 0; r < 32; ++r) {
      float4 a = *(const float4*)&tile[r][k];
      acc0[r] = fmaf(a.x, w00, acc0[r]); acc0[r] = fmaf(a.y, w01, acc0[r]);
      acc0[r] = fmaf(a.z, w02, acc0[r]); acc0[r] = fmaf(a.w, w03, acc0[r]);
      acc1[r] = fmaf(a.x, w10, acc1[r]); acc1[r] = fmaf(a.y, w11, acc1[r]);
      acc1[r] = fmaf(a.z, w12, acc1[r]); acc1[r] = fmaf(a.w, w13, acc1[r]);
    }
  }
#pragma unroll
  for (int kk = 128; kk < 131; ++kk) {
    float w0 = W[kk*256+c0], w1 = W[kk*256+c1];
#pragma unroll
    for (int r = 0; r < 32; ++r) {
      float a = tile[r][kk];
      acc0[r] = fmaf(a, w0, acc0[r]);
      acc1[r] = fmaf(a, w1, acc1[r]);
    }
  }
#pragma unroll
  for (int r = 0; r < 32; ++r) {
    if (BF16OUT) {
      __hip_bfloat16* o = (__hip_bfloat16*)outp;
      o[(size_t)(r0+r)*256 + c0] = __float2bfloat16(acc0[r]);
      o[(size_t)(r0+r)*256 + c1] = __float2bfloat16(acc1[r]);
    } else {
      float* o = (float*)outp;
      o[(size_t)(r0+r)*256 + c0] = acc0[r];
      o[(size_t)(r0+r)*256 + c1] = acc1[r];
    }
  }
}

__global__ void wdiff_kernel(const float* __restrict__ W, float* __restrict__ Wd) {
  int i = blockIdx.x * 256 + threadIdx.x;
  Wd[i] = W[131*256 + i] - W[i];
}

// Per-batch stats (fallback path).
__global__ __launch_bounds__(256) void stats_kernel(
    const __hip_bfloat16* __restrict__ Pb, const int* __restrict__ knn,
    float* __restrict__ outFeat, float* __restrict__ psum, float* __restrict__ psq,
    int qq0, int prow) {
  const int c = threadIdx.x;
  float s = 0.f, s2 = 0.f;
  const int q0 = qq0 + blockIdx.x * 16;
  for (int q = 0; q < 16; ++q) {
    int qq = q0 + q;
    float qc = outFeat[(size_t)qq*256 + c];
    float m = -1e30f;
    const int* kn = knn + (size_t)qq * KNN;
#pragma unroll
    for (int k = 0; k < KNN; ++k) {
      int idx = kn[k];
      float v = __bfloat162float(Pb[(size_t)idx*256 + c]) + qc;
      m = fmaxf(m, v);
      s += v;
      s2 = fmaf(v, v, s2);
    }
    outFeat[(size_t)qq*256 + c] = m;
  }
  psum[(size_t)(prow + blockIdx.x)*256 + c] = s;
  psq [(size_t)(prow + blockIdx.x)*256 + c] = s2;
}

// All-batches stats (fused path): 512 blocks x 16 queries.
__global__ __launch_bounds__(256) void stats_all_kernel(
    const __hip_bfloat16* __restrict__ Pall,  // [4][8192][256]
    const int* __restrict__ knn, float* __restrict__ outFeat,
    float* __restrict__ psum, float* __restrict__ psq) {
  const int c = threadIdx.x;
  float s = 0.f, s2 = 0.f;
  const int q0 = blockIdx.x * 16;
  for (int q = 0; q < 16; ++q) {
    int qq = q0 + q;
    int b = qq >> 11;
    const __hip_bfloat16* Pb = Pall + (size_t)b * NPTS * 256;
    float qc = outFeat[(size_t)qq*256 + c];
    float m = -1e30f;
    const int* kn = knn + (size_t)qq * KNN;
#pragma unroll
    for (int k = 0; k < KNN; ++k) {
      int idx = kn[k];                      // batch-local point index
      float v = __bfloat162float(Pb[(size_t)idx*256 + c]) + qc;
      m = fmaxf(m, v);
      s += v;
      s2 = fmaf(v, v, s2);
    }
    outFeat[(size_t)qq*256 + c] = m;
  }
  psum[(size_t)blockIdx.x*256 + c] = s;
  psq [(size_t)blockIdx.x*256 + c] = s2;
}

__global__ __launch_bounds__(256) void reduce_stats_kernel(
    const float* __restrict__ psum, const float* __restrict__ psq,
    const float* __restrict__ gamma, const float* __restrict__ beta,
    float* __restrict__ ss) {
  const int c = blockIdx.x, t = threadIdx.x;
  float s  = psum[(size_t)t*256 + c] + psum[(size_t)(t+256)*256 + c];
  float s2 = psq [(size_t)t*256 + c] + psq [(size_t)(t+256)*256 + c];
#pragma unroll
  for (int off = 32; off >= 1; off >>= 1) {
    s  += __shfl_xor(s,  off);
    s2 += __shfl_xor(s2, off);
  }
  __shared__ float as[4], as2[4];
  const int lane = t & 63, wid = t >> 6;
  if (lane == 0) { as[wid] = s; as2[wid] = s2; }
  __syncthreads();
  if (t == 0) {
    float S  = (as[0]+as[1]) + (as[2]+as[3]);
    float S2 = (as2[0]+as2[1]) + (as2[2]+as2[3]);
    const float inv = 1.f / 163840.f;  // B*S*K
    float mean = S * inv;
    float var  = S2 * inv - mean * mean;
    float sc = rsqrtf(var + 1e-5f) * gamma[c];
    ss[c]       = sc;
    ss[256 + c] = beta[c] - mean * sc;
  }
}

__global__ __launch_bounds__(256) void finalize_kernel(
    float* __restrict__ f, const float* __restrict__ ss) {
  int e = blockIdx.x * 256 + threadIdx.x;
  float v = fmaf(f[e], ss[threadIdx.x], ss[256 + threadIdx.x]);
  f[e] = v > 0.f ? v : 0.f;
}

extern "C" void kernel_launch(void* const* d_in, const int* in_sizes, int n_in,
                              void* d_out, int out_size, void* d_ws, size_t ws_size,
                              hipStream_t stream) {
  const float* xyz      = (const float*)d_in[0];
  const float* feat     = (const float*)d_in[1];
  const float* conv_w   = (const float*)d_in[2];   // [262][256]
  const float* bn_gamma = (const float*)d_in[3];
  const float* bn_beta  = (const float*)d_in[4];
  const int*   far0     = (const int*)d_in[5];

  char* ws = (char*)d_ws;
  int*   sample_int = (int*)  (ws + 0);
  int*   knn        = (int*)  (ws + 32768);
  float* Wd         = (float*)(ws + 688128);
  float* psum       = (float*)(ws + 822272);
  float* psq        = (float*)(ws + 1346560);
  float* ss         = (float*)(ws + 1870848);
  __hip_bfloat16* Pb = (__hip_bfloat16*)(ws + 2097152);  // per-batch 4.19MB or all 16.8MB

  float* out     = (float*)d_out;
  float* outFeat = out + 24576;                  // new_feat region [4][2048][256]

  const bool fused = ws_size >= (size_t)(2097152 + 33554432/2);  // 2MB + 16.8MB

  if (fused) {
    // one launch: fps (blocks 0-3) + matmulP (4..131) + wdiff (132..164)
    mega_kernel<<<dim3(4 + NM_BLOCKS + 33), dim3(1024), 0, stream>>>(
        xyz, far0, feat, conv_w, sample_int, out, Pb, Wd, NM_BLOCKS);
    knn_kernel<<<dim3(4096), dim3(256), 0, stream>>>(xyz, sample_int, knn);
    matmul131_kernel<false><<<dim3(256), dim3(128), 0, stream>>>(
        feat, xyz, sample_int, Wd, (void*)outFeat);              // Q
    stats_all_kernel<<<dim3(512), dim3(256), 0, stream>>>(
        Pb, knn, outFeat, psum, psq);
  } else {
    mega_kernel<<<dim3(4 + 33), dim3(1024), 0, stream>>>(
        xyz, far0, feat, conv_w, sample_int, out, Pb, Wd, 0);    // fps + wdiff only
    knn_kernel<<<dim3(4096), dim3(256), 0, stream>>>(xyz, sample_int, knn);
    matmul131_kernel<false><<<dim3(256), dim3(128), 0, stream>>>(
        feat, xyz, sample_int, Wd, (void*)outFeat);              // Q
    for (int b = 0; b < 4; ++b) {
      matmul131_kernel<true><<<dim3(256), dim3(128), 0, stream>>>(
          feat + (size_t)b*NPTS*128, xyz + (size_t)b*NPTS*3,
          (const int*)nullptr, conv_w, (void*)Pb);
      stats_kernel<<<dim3(128), dim3(256), 0, stream>>>(
          Pb, knn + (size_t)b*NSAMP*KNN, outFeat + (size_t)b*NSAMP*256,
          psum, psq, 0, b*128);
    }
  }

  reduce_stats_kernel<<<dim3(256), dim3(256), 0, stream>>>(psum, psq, bn_gamma, bn_beta, ss);
  finalize_kernel   <<<dim3(8192), dim3(256), 0, stream>>>(outFeat, ss);
}

// Round 17
// 1881.875 us; speedup vs baseline: 1.0622x; 1.0622x over previous
//
#include <hip/hip_runtime.h>
#include <hip/hip_bf16.h>

// B=4, N=8192, S=2048, C=128, c_in=131, c_out=256, K=20 (fixed by setup_inputs).
// Algebra: h = (knn_feat-center)@W1 + center@W2 = P[knn_idx] + Q.
// BN(gamma>0) and ReLU monotone => max_k commutes.
//
// r16 decomposition: overlap (matmulP/wdiff in fps's shadow) = -44us on rest;
// hierarchical pretest = +125us on fps (provably never skips more than the
// per-lane + __any path; pure serial-chain overhead). r17 = overlap + v10 fps.

#define NPTS   8192
#define NSAMP  2048
#define KNN    20

typedef unsigned long long u64;
typedef unsigned int u32;
typedef unsigned short u16;

// ---------- DPP reduction helpers (wave64; validated on HW rounds 5-16) ----------
template<int CTRL, int RM>
__device__ __forceinline__ u64 dpp_kmax(u64 k) {
  unsigned lo = (unsigned)k, hi = (unsigned)(k >> 32);
  unsigned lo2 = (unsigned)__builtin_amdgcn_update_dpp((int)lo, (int)lo, CTRL, RM, 0xf, false);
  unsigned hi2 = (unsigned)__builtin_amdgcn_update_dpp((int)hi, (int)hi, CTRL, RM, 0xf, false);
  u64 o = ((u64)hi2 << 32) | lo2;
  return o > k ? o : k;
}
template<int CTRL, int RM>
__device__ __forceinline__ u64 dpp_kmin(u64 k) {
  unsigned lo = (unsigned)k, hi = (unsigned)(k >> 32);
  unsigned lo2 = (unsigned)__builtin_amdgcn_update_dpp((int)lo, (int)lo, CTRL, RM, 0xf, false);
  unsigned hi2 = (unsigned)__builtin_amdgcn_update_dpp((int)hi, (int)hi, CTRL, RM, 0xf, false);
  u64 o = ((u64)hi2 << 32) | lo2;
  return o < k ? o : k;
}
__device__ __forceinline__ u64 umax64(u64 a, u64 b) { return a > b ? a : b; }

__device__ __forceinline__ unsigned mspread4(unsigned q) {  // 4b -> every 3rd bit
  return (q & 1u) | ((q & 2u) << 2) | ((q & 4u) << 4) | ((q & 8u) << 6);
}

// Mega kernel: blocks 0-3 = FPS v10 (measured best); 4..3+NM = matmulP (bf16,
// 256 rows/block, 8x 32-row subtiles); rest = wdiff. No inter-block deps.
#define NM_BLOCKS 128
__global__ __launch_bounds__(1024, 1) void mega_kernel(
    const float* __restrict__ xyz, const int* __restrict__ farthest0,
    const float* __restrict__ feat, const float* __restrict__ conv_w,
    int* __restrict__ sample_int, float* __restrict__ out,
    __hip_bfloat16* __restrict__ Pb, float* __restrict__ Wd, int nmatmul) {
  __shared__ u64 smem8[17984];              // 143,872 B (fps 143,388 / matmul 135,168)
  char* smem = (char*)smem8;
  const int bid = blockIdx.x, tid = threadIdx.x;

  if (bid >= 4) {
    if (bid - 4 < nmatmul) {
      // ---- matmulP: OUT[row,c] = sum_k feat_aug[row][k] * W1[k*256+c], bf16 out ----
      float* tile = (float*)smem + (tid >> 7) * (32 * 132);  // [32][132] per group
      const int gtid = tid & 127;
      const int r0 = (bid - 4) * 256 + (tid >> 7) * 32;
      for (int i = gtid; i < 32 * 131; i += 128) {
        int r = i / 131;
        int k = i - r * 131;
        int src = r0 + r;                  // global row 0..32767
        float v = (k < 128) ? feat[(size_t)src * 128 + k]
                            : xyz[(size_t)src * 3 + (k - 128)];
        tile[r * 132 + k] = v;
      }
      __syncthreads();
      float acc0[32], acc1[32];
#pragma unroll
      for (int r = 0; r < 32; ++r) { acc0[r] = 0.f; acc1[r] = 0.f; }
      const int c0 = gtid, c1 = gtid + 128;
      for (int k = 0; k < 128; k += 4) {
        float w00 = conv_w[(k+0)*256+c0], w01 = conv_w[(k+1)*256+c0], w02 = conv_w[(k+2)*256+c0], w03 = conv_w[(k+3)*256+c0];
        float w10 = conv_w[(k+0)*256+c1], w11 = conv_w[(k+1)*256+c1], w12 = conv_w[(k+2)*256+c1], w13 = conv_w[(k+3)*256+c1];
#pragma unroll
        for (int r = 0; r < 32; ++r) {
          float4 a = *(const float4*)&tile[r * 132 + k];
          acc0[r] = fmaf(a.x, w00, acc0[r]); acc0[r] = fmaf(a.y, w01, acc0[r]);
          acc0[r] = fmaf(a.z, w02, acc0[r]); acc0[r] = fmaf(a.w, w03, acc0[r]);
          acc1[r] = fmaf(a.x, w10, acc1[r]); acc1[r] = fmaf(a.y, w11, acc1[r]);
          acc1[r] = fmaf(a.z, w12, acc1[r]); acc1[r] = fmaf(a.w, w13, acc1[r]);
        }
      }
#pragma unroll
      for (int kk = 128; kk < 131; ++kk) {
        float w0 = conv_w[kk*256+c0], w1 = conv_w[kk*256+c1];
#pragma unroll
        for (int r = 0; r < 32; ++r) {
          float a = tile[r * 132 + kk];
          acc0[r] = fmaf(a, w0, acc0[r]);
          acc1[r] = fmaf(a, w1, acc1[r]);
        }
      }
#pragma unroll
      for (int r = 0; r < 32; ++r) {
        Pb[(size_t)(r0 + r) * 256 + c0] = __float2bfloat16(acc0[r]);
        Pb[(size_t)(r0 + r) * 256 + c1] = __float2bfloat16(acc1[r]);
      }
    } else {
      // ---- wdiff: Wd = W2 - W1 ----
      int i = (bid - 4 - nmatmul) * 1024 + tid;
      if (i < 131 * 256) Wd[i] = conv_w[131 * 256 + i] - conv_w[i];
    }
    return;
  }

  // ================= FPS v10 (blocks 0-3; measured best 1525us) =================
  float* sxyz  = (float*)smem;              // [24576]
  u16*   sidxr = (u16*)(smem + 98304);      // [8192]
  u32*   s_samp= (u32*)(smem + 114688);     // [2048]
  u32*   hist  = (u32*)(smem + 122880);     // [4096]
  u32*   part  = (u32*)(smem + 139264);     // [1024]
  u64*   slot  = (u64*)(smem + 143360);     // [3]
  int*   s_isp = (int*)(smem + 143384);
  const int b = bid, lane = tid & 63;
  const float* xb = xyz + (size_t)b * NPTS * 3;

  // ---- counting sort by 12-bit Morton (4 bits/axis, range [-5.2, 5.2]) ----
  for (int i = tid; i < 4096; i += 1024) hist[i] = 0u;
  if (tid < 3) slot[tid] = 0ull;
  __syncthreads();

  float ox[8], oy[8], oz[8];
  int cell[8];
#pragma unroll
  for (int j = 0; j < 8; ++j) {
    int p = tid * 8 + j;
    float x = xb[3*p], y = xb[3*p+1], z = xb[3*p+2];
    ox[j] = x; oy[j] = y; oz[j] = z;
    unsigned qx = (unsigned)(int)fminf(fmaxf((x + 5.2f) * 1.5384615f, 0.f), 15.f);
    unsigned qy = (unsigned)(int)fminf(fmaxf((y + 5.2f) * 1.5384615f, 0.f), 15.f);
    unsigned qz = (unsigned)(int)fminf(fmaxf((z + 5.2f) * 1.5384615f, 0.f), 15.f);
    cell[j] = (int)(mspread4(qx) | (mspread4(qy) << 1) | (mspread4(qz) << 2));
    atomicAdd(&hist[cell[j]], 1u);
  }
  __syncthreads();

  u32 h0 = hist[4*tid], h1 = hist[4*tid+1], h2 = hist[4*tid+2], h3 = hist[4*tid+3];
  u32 mysum = h0 + h1 + h2 + h3;
  part[tid] = mysum;
  __syncthreads();
  for (int off = 1; off < 1024; off <<= 1) {
    u32 u = (tid >= off) ? part[tid - off] : 0u;
    u32 v = part[tid];
    __syncthreads();
    part[tid] = u + v;
    __syncthreads();
  }
  u32 base = part[tid] - mysum;
  hist[4*tid]   = base;
  hist[4*tid+1] = base + h0;
  hist[4*tid+2] = base + h0 + h1;
  hist[4*tid+3] = base + h0 + h1 + h2;
  __syncthreads();

#pragma unroll
  for (int j = 0; j < 8; ++j) {
    u32 p = atomicAdd(&hist[cell[j]], 1u);
    sxyz[3*p] = ox[j]; sxyz[3*p+1] = oy[j]; sxyz[3*p+2] = oz[j];
    sidxr[p] = (u16)(tid * 8 + j);
  }
  __syncthreads();

  const int cur0 = farthest0[b];
#pragma unroll
  for (int j = 0; j < 8; ++j) {
    int p = tid * 8 + j;
    if ((int)sidxr[p] == cur0) *s_isp = p;  // exactly one writer
  }

  // ---- per-lane bucket: 8 sorted-consecutive points + tight per-lane bbox ----
  float px[8], py[8], pz[8], dist[8];
  u32 low32[8];                             // (~orig:13)<<13 | sp:13
#pragma unroll
  for (int j = 0; j < 8; ++j) {
    int p = tid * 8 + j;
    px[j] = sxyz[3*p]; py[j] = sxyz[3*p+1]; pz[j] = sxyz[3*p+2];
    low32[j] = (((~(u32)sidxr[p]) & 0x1FFFu) << 13) | (u32)p;
    dist[j] = 1e10f;                        // reference init 10000000000.0
  }
  float lxmin = px[0], lxmax = px[0], lymin = py[0], lymax = py[0], lzmin = pz[0], lzmax = pz[0];
#pragma unroll
  for (int j = 1; j < 8; ++j) {
    lxmin = fminf(lxmin, px[j]); lxmax = fmaxf(lxmax, px[j]);
    lymin = fminf(lymin, py[j]); lymax = fmaxf(lymax, py[j]);
    lzmin = fminf(lzmin, pz[j]); lzmax = fmaxf(lzmax, pz[j]);
  }

  u64 klane = ((u64)__float_as_uint(1e10f) << 32);  // per-lane cached max key
  u64 kw    = ((u64)__float_as_uint(1e10f) << 32);  // lane63's wave max cache
  __syncthreads();                                  // s_isp visible

  int cur_sp = *s_isp;
  u32 cur_pack = ((u32)cur0 << 13) | (u32)cur_sp;

  for (int it = 0; it < NSAMP; ++it) {
    if (tid == 0) s_samp[it] = cur_pack;   // scan emits carry (index before update)
    if (it == NSAMP - 1) break;
    if (tid == 64) slot[(it+2)%3] = 0ull;  // rotation proven race-free (v6-v14)
    float3 c3 = *(const float3*)&sxyz[3*cur_sp];   // one ds_read_b96, uniform
    float cx = c3.x, cy = c3.y, cz = c3.z;

    // per-lane exact skip: bound >= lane max dist => nothing in bucket changes
    float gx = fmaxf(fmaxf(__fsub_rn(lxmin, cx), __fsub_rn(cx, lxmax)), 0.f);
    float gy = fmaxf(fmaxf(__fsub_rn(lymin, cy), __fsub_rn(cy, lymax)), 0.f);
    float gz = fmaxf(fmaxf(__fsub_rn(lzmin, cz), __fsub_rn(cz, lzmax)), 0.f);
    float bound = __fadd_rn(__fadd_rn(__fmul_rn(gx,gx), __fmul_rn(gy,gy)), __fmul_rn(gz,gz));
    float ub = __uint_as_float((u32)(klane >> 32));   // hi reg, no shift emitted
    bool live = !(__fmul_rn(bound, 0.999999f) >= ub);

    if (__any(live)) {                     // whole-wave execz skip when all dead
      if (live) {
        // strict IEEE update, no FMA contraction (matches reference bit-exact)
#pragma unroll
        for (int j = 0; j < 8; ++j) {
          float dx = __fsub_rn(px[j], cx);
          float dy = __fsub_rn(py[j], cy);
          float dz = __fsub_rn(pz[j], cz);
          float d  = __fadd_rn(__fadd_rn(__fmul_rn(dx,dx), __fmul_rn(dy,dy)), __fmul_rn(dz,dz));
          dist[j] = fminf(dist[j], d);
        }
        u64 k0 = ((u64)__float_as_uint(dist[0]) << 32) | low32[0];
        u64 k1 = ((u64)__float_as_uint(dist[1]) << 32) | low32[1];
        u64 k2 = ((u64)__float_as_uint(dist[2]) << 32) | low32[2];
        u64 k3 = ((u64)__float_as_uint(dist[3]) << 32) | low32[3];
        u64 k4 = ((u64)__float_as_uint(dist[4]) << 32) | low32[4];
        u64 k5 = ((u64)__float_as_uint(dist[5]) << 32) | low32[5];
        u64 k6 = ((u64)__float_as_uint(dist[6]) << 32) | low32[6];
        u64 k7 = ((u64)__float_as_uint(dist[7]) << 32) | low32[7];
        klane = umax64(umax64(umax64(k0,k1), umax64(k2,k3)),
                       umax64(umax64(k4,k5), umax64(k6,k7)));
      }
      u64 k = klane;                       // dead lanes contribute valid cache
      k = dpp_kmax<0xB1, 0xf>(k);
      k = dpp_kmax<0x4E, 0xf>(k);
      k = dpp_kmax<0x124, 0xf>(k);
      k = dpp_kmax<0x128, 0xf>(k);
      k = dpp_kmax<0x142, 0xa>(k);
      k = dpp_kmax<0x143, 0xc>(k);
      kw = k;                              // lane 63 holds the wave max
    }
    if (lane == 63) atomicMax(&slot[(it+1)%3], kw);
    __syncthreads();                       // the ONLY barrier per iteration
    u64 wk = slot[(it+1)%3];               // uniform LDS read
    u32 wlo = (u32)wk;
    cur_sp = (int)(wlo & 0x1FFFu);
    u32 org = (~(wlo >> 13)) & 0x1FFFu;
    cur_pack = (org << 13) | (u32)cur_sp;
  }

  __syncthreads();
  float* outxyz = out + (size_t)b * NSAMP * 3;
  float* outidx = out + 24576 + 2097152 + (size_t)b * NSAMP;
  for (int it = tid; it < NSAMP; it += 1024) {
    u32 s = s_samp[it];
    int org = (int)(s >> 13), sp = (int)(s & 0x1FFFu);
    sample_int[(b << 11) + it] = org;
    outidx[it] = (float)org;
    outxyz[3*it]   = sxyz[3*sp];
    outxyz[3*it+1] = sxyz[3*sp+1];
    outxyz[3*it+2] = sxyz[3*sp+2];
  }
}

// kNN v5 (r10-r16): 2 waves per query, exact rank-merge of two sorted top-20 lists.
__global__ __launch_bounds__(256, 1) void knn_kernel(
    const float* __restrict__ xyz, const int* __restrict__ sample_int,
    int* __restrict__ knn_out) {
  __shared__ u64 lists[2][2][KNN];
  const int tid  = threadIdx.x;
  const int lane = tid & 63, w = tid >> 6;
  const int ql   = w >> 1;                 // local query 0..1
  const int ch   = w & 1;                  // chunk 0..1
  const int qq   = blockIdx.x * 2 + ql;
  const int b    = qq >> 11;
  const float* xb = xyz + (size_t)b * NPTS * 3;
  const int sidx = sample_int[qq];
  const float sx = xb[3*sidx], sy = xb[3*sidx+1], sz = xb[3*sidx+2];
  const float sqs = __fadd_rn(__fadd_rn(__fmul_rn(sx,sx), __fmul_rn(sy,sy)), __fmul_rn(sz,sz));

  const int pbase = ch * 4096;
  float d[64];
#pragma unroll
  for (int i = 0; i < 64; ++i) {
    int p = pbase + i*64 + lane;
    float x = xb[3*p], y = xb[3*p+1], z = xb[3*p+2];
    float dot = __fadd_rn(__fadd_rn(__fmul_rn(sx,x), __fmul_rn(sy,y)), __fmul_rn(sz,z));
    float sqx = __fadd_rn(__fadd_rn(__fmul_rn(x,x), __fmul_rn(y,y)), __fmul_rn(z,z));
    d[i] = __fadd_rn(__fsub_rn(sqs, __fmul_rn(2.0f, dot)), sqx);  // (||s||^2-2dot)+||x||^2
  }
  u64 msk = 0ull;
  for (int kk = 0; kk < KNN; ++kk) {
    float bv = 1e30f; int bs = 0;
#pragma unroll
    for (int i = 0; i < 64; ++i) {
      float dc = (msk & (1ull << i)) ? 1e30f : d[i];
      if (dc < bv) { bv = dc; bs = i; }   // strict <: smallest slot on ties
    }
    unsigned gi = (unsigned)(pbase + bs*64 + lane);
    u64 key = ((u64)__float_as_uint(bv) << 32) | gi;
    key = dpp_kmin<0xB1, 0xf>(key);
    key = dpp_kmin<0x4E, 0xf>(key);
    key = dpp_kmin<0x124, 0xf>(key);
    key = dpp_kmin<0x128, 0xf>(key);
    key = dpp_kmin<0x142, 0xa>(key);
    key = dpp_kmin<0x143, 0xc>(key);
    unsigned glo = (unsigned)__builtin_amdgcn_readlane((int)(unsigned)key, 63);
    unsigned ghi = (unsigned)__builtin_amdgcn_readlane((int)(unsigned)(key >> 32), 63);
    if (lane == (int)(glo & 63u)) msk |= 1ull << ((glo - pbase) >> 6);
    if (lane == 0) lists[ql][ch][kk] = ((u64)ghi << 32) | glo;
  }
  __syncthreads();
  if (ch == 0) {
    u64 mykey = ~0ull; int rank = 64;
    if (lane < 40) {
      int li = lane >= 20 ? 1 : 0;
      int e  = li ? lane - 20 : lane;
      mykey = lists[ql][li][e];
      int cnt = e;
      const u64* oth = &lists[ql][li ^ 1][0];
#pragma unroll
      for (int j = 0; j < KNN; ++j) cnt += (oth[j] < mykey) ? 1 : 0;
      rank = cnt;
    }
    if (rank < KNN) knn_out[(size_t)qq * KNN + rank] = (int)(mykey & 0xFFFFFFFFull);
  }
}

// matmul131 (generic): used for Q = center@(W2-W1) and the non-fused fallback.
template<bool BF16OUT>
__global__ __launch_bounds__(128) void matmul131_kernel(
    const float* __restrict__ featb, const float* __restrict__ xyzb,
    const int* __restrict__ gidx,
    const float* __restrict__ W, void* __restrict__ outp) {
  __shared__ float tile[32][132];
  const int tid = threadIdx.x;
  const int r0  = blockIdx.x << 5;
  for (int i = tid; i < 32*131; i += 128) {
    int r = i / 131;
    int k = i - r*131;
    int row = r0 + r;
    int src;
    if (gidx) { int bb = row >> 11; src = (bb << 13) + gidx[row]; }
    else      { src = row; }
    float v = (k < 128) ? featb[(size_t)src*128 + k]
                        : xyzb[(size_t)src*3 + (k-128)];
    tile[r][k] = v;
  }
  __syncthreads();
  float acc0[32], acc1[32];
#pragma unroll
  for (int r = 0; r < 32; ++r) { acc0[r] = 0.f; acc1[r] = 0.f; }
  const int c0 = tid, c1 = tid + 128;
  for (int k = 0; k < 128; k += 4) {
    float w00 = W[(k+0)*256+c0], w01 = W[(k+1)*256+c0], w02 = W[(k+2)*256+c0], w03 = W[(k+3)*256+c0];
    float w10 = W[(k+0)*256+c1], w11 = W[(k+1)*256+c1], w12 = W[(k+2)*256+c1], w13 = W[(k+3)*256+c1];
#pragma unroll
    for (int r = 0; r < 32; ++r) {
      float4 a = *(const float4*)&tile[r][k];
      acc0[r] = fmaf(a.x, w00, acc0[r]); acc0[r] = fmaf(a.y, w01, acc0[r]);
      acc0[r] = fmaf(a.z, w02, acc0[r]); acc0[r] = fmaf(a.w, w03, acc0[r]);
      acc1[r] = fmaf(a.x, w10, acc1[r]); acc1[r] = fmaf(a.y, w11, acc1[r]);
      acc1[r] = fmaf(a.z, w12, acc1[r]); acc1[r] = fmaf(a.w, w13, acc1[r]);
    }
  }
#pragma unroll
  for (int kk = 128; kk < 131; ++kk) {
    float w0 = W[kk*256+c0], w1 = W[kk*256+c1];
#pragma unroll
    for (int r = 0; r < 32; ++r) {
      float a = tile[r][kk];
      acc0[r] = fmaf(a, w0, acc0[r]);
      acc1[r] = fmaf(a, w1, acc1[r]);
    }
  }
#pragma unroll
  for (int r = 0; r < 32; ++r) {
    if (BF16OUT) {
      __hip_bfloat16* o = (__hip_bfloat16*)outp;
      o[(size_t)(r0+r)*256 + c0] = __float2bfloat16(acc0[r]);
      o[(size_t)(r0+r)*256 + c1] = __float2bfloat16(acc1[r]);
    } else {
      float* o = (float*)outp;
      o[(size_t)(r0+r)*256 + c0] = acc0[r];
      o[(size_t)(r0+r)*256 + c1] = acc1[r];
    }
  }
}

// Per-batch stats (fallback path).
__global__ __launch_bounds__(256) void stats_kernel(
    const __hip_bfloat16* __restrict__ Pb, const int* __restrict__ knn,
    float* __restrict__ outFeat, float* __restrict__ psum, float* __restrict__ psq,
    int qq0, int prow) {
  const int c = threadIdx.x;
  float s = 0.f, s2 = 0.f;
  const int q0 = qq0 + blockIdx.x * 16;
  for (int q = 0; q < 16; ++q) {
    int qq = q0 + q;
    float qc = outFeat[(size_t)qq*256 + c];
    float m = -1e30f;
    const int* kn = knn + (size_t)qq * KNN;
#pragma unroll
    for (int k = 0; k < KNN; ++k) {
      int idx = kn[k];
      float v = __bfloat162float(Pb[(size_t)idx*256 + c]) + qc;
      m = fmaxf(m, v);
      s += v;
      s2 = fmaf(v, v, s2);
    }
    outFeat[(size_t)qq*256 + c] = m;
  }
  psum[(size_t)(prow + blockIdx.x)*256 + c] = s;
  psq [(size_t)(prow + blockIdx.x)*256 + c] = s2;
}

// All-batches stats (fused path): 512 blocks x 16 queries.
__global__ __launch_bounds__(256) void stats_all_kernel(
    const __hip_bfloat16* __restrict__ Pall,  // [4][8192][256]
    const int* __restrict__ knn, float* __restrict__ outFeat,
    float* __restrict__ psum, float* __restrict__ psq) {
  const int c = threadIdx.x;
  float s = 0.f, s2 = 0.f;
  const int q0 = blockIdx.x * 16;
  for (int q = 0; q < 16; ++q) {
    int qq = q0 + q;
    int b = qq >> 11;
    const __hip_bfloat16* Pb = Pall + (size_t)b * NPTS * 256;
    float qc = outFeat[(size_t)qq*256 + c];
    float m = -1e30f;
    const int* kn = knn + (size_t)qq * KNN;
#pragma unroll
    for (int k = 0; k < KNN; ++k) {
      int idx = kn[k];                      // batch-local point index
      float v = __bfloat162float(Pb[(size_t)idx*256 + c]) + qc;
      m = fmaxf(m, v);
      s += v;
      s2 = fmaf(v, v, s2);
    }
    outFeat[(size_t)qq*256 + c] = m;
  }
  psum[(size_t)blockIdx.x*256 + c] = s;
  psq [(size_t)blockIdx.x*256 + c] = s2;
}

__global__ __launch_bounds__(256) void reduce_stats_kernel(
    const float* __restrict__ psum, const float* __restrict__ psq,
    const float* __restrict__ gamma, const float* __restrict__ beta,
    float* __restrict__ ss) {
  const int c = blockIdx.x, t = threadIdx.x;
  float s  = psum[(size_t)t*256 + c] + psum[(size_t)(t+256)*256 + c];
  float s2 = psq [(size_t)t*256 + c] + psq [(size_t)(t+256)*256 + c];
#pragma unroll
  for (int off = 32; off >= 1; off >>= 1) {
    s  += __shfl_xor(s,  off);
    s2 += __shfl_xor(s2, off);
  }
  __shared__ float as[4], as2[4];
  const int lane = t & 63, wid = t >> 6;
  if (lane == 0) { as[wid] = s; as2[wid] = s2; }
  __syncthreads();
  if (t == 0) {
    float S  = (as[0]+as[1]) + (as[2]+as[3]);
    float S2 = (as2[0]+as2[1]) + (as2[2]+as2[3]);
    const float inv = 1.f / 163840.f;  // B*S*K
    float mean = S * inv;
    float var  = S2 * inv - mean * mean;
    float sc = rsqrtf(var + 1e-5f) * gamma[c];
    ss[c]       = sc;
    ss[256 + c] = beta[c] - mean * sc;
  }
}

__global__ __launch_bounds__(256) void finalize_kernel(
    float* __restrict__ f, const float* __restrict__ ss) {
  int e = blockIdx.x * 256 + threadIdx.x;
  float v = fmaf(f[e], ss[threadIdx.x], ss[256 + threadIdx.x]);
  f[e] = v > 0.f ? v : 0.f;
}

extern "C" void kernel_launch(void* const* d_in, const int* in_sizes, int n_in,
                              void* d_out, int out_size, void* d_ws, size_t ws_size,
                              hipStream_t stream) {
  const float* xyz      = (const float*)d_in[0];
  const float* feat     = (const float*)d_in[1];
  const float* conv_w   = (const float*)d_in[2];   // [262][256]
  const float* bn_gamma = (const float*)d_in[3];
  const float* bn_beta  = (const float*)d_in[4];
  const int*   far0     = (const int*)d_in[5];

  char* ws = (char*)d_ws;
  int*   sample_int = (int*)  (ws + 0);
  int*   knn        = (int*)  (ws + 32768);
  float* Wd         = (float*)(ws + 688128);
  float* psum       = (float*)(ws + 822272);
  float* psq        = (float*)(ws + 1346560);
  float* ss         = (float*)(ws + 1870848);
  __hip_bfloat16* Pb = (__hip_bfloat16*)(ws + 2097152);  // per-batch 4.19MB or all 16.8MB

  float* out     = (float*)d_out;
  float* outFeat = out + 24576;                  // new_feat region [4][2048][256]

  const bool fused = ws_size >= (size_t)(2097152 + 33554432/2);  // 2MB + 16.8MB

  if (fused) {
    // one launch: fps (blocks 0-3) + matmulP (4..131) + wdiff (132..164)
    mega_kernel<<<dim3(4 + NM_BLOCKS + 33), dim3(1024), 0, stream>>>(
        xyz, far0, feat, conv_w, sample_int, out, Pb, Wd, NM_BLOCKS);
    knn_kernel<<<dim3(4096), dim3(256), 0, stream>>>(xyz, sample_int, knn);
    matmul131_kernel<false><<<dim3(256), dim3(128), 0, stream>>>(
        feat, xyz, sample_int, Wd, (void*)outFeat);              // Q
    stats_all_kernel<<<dim3(512), dim3(256), 0, stream>>>(
        Pb, knn, outFeat, psum, psq);
  } else {
    mega_kernel<<<dim3(4 + 33), dim3(1024), 0, stream>>>(
        xyz, far0, feat, conv_w, sample_int, out, Pb, Wd, 0);    // fps + wdiff only
    knn_kernel<<<dim3(4096), dim3(256), 0, stream>>>(xyz, sample_int, knn);
    matmul131_kernel<false><<<dim3(256), dim3(128), 0, stream>>>(
        feat, xyz, sample_int, Wd, (void*)outFeat);              // Q
    for (int b = 0; b < 4; ++b) {
      matmul131_kernel<true><<<dim3(256), dim3(128), 0, stream>>>(
          feat + (size_t)b*NPTS*128, xyz + (size_t)b*NPTS*3,
          (const int*)nullptr, conv_w, (void*)Pb);
      stats_kernel<<<dim3(128), dim3(256), 0, stream>>>(
          Pb, knn + (size_t)b*NSAMP*KNN, outFeat + (size_t)b*NSAMP*256,
          psum, psq, 0, b*128);
    }
  }

  reduce_stats_kernel<<<dim3(256), dim3(256), 0, stream>>>(psum, psq, bn_gamma, bn_beta, ss);
  finalize_kernel   <<<dim3(8192), dim3(256), 0, stream>>>(outFeat, ss);
}